// Round 1
// baseline (507.065 us; speedup 1.0000x reference)
//
#include <hip/hip_runtime.h>
#include <hip/hip_bf16.h>

// Problem constants (from reference): B=16, C=64, H=W=128, K=9, KN=64
#define NB   16          // batch
#define NC   64          // channels
#define NH   128
#define NW   128
#define NHW  16384       // H*W (pixels)
#define CHW  1048576     // C*H*W (per-batch x elements)
#define KC   576         // K*C (gather width / GEMM K)
#define KN   64          // output channels (GEMM M)

// ---------------------------------------------------------------------------
// Kernel 1: transpose x [B][CHW] -> xT [CHW][B]  (so one gather index fetches
// all 16 batches as one contiguous 64B line)
// ---------------------------------------------------------------------------
__global__ __launch_bounds__(256) void transpose_x_kernel(
    const float* __restrict__ x, float* __restrict__ xT) {
  const int i = blockIdx.x * 256 + threadIdx.x;  // CHW index
  float v[NB];
#pragma unroll
  for (int b = 0; b < NB; ++b) v[b] = x[(size_t)b * CHW + i];  // coalesced per b
  float4* dst = (float4*)(xT + (size_t)i * NB);                // 64B per thread
#pragma unroll
  for (int j = 0; j < 4; ++j)
    dst[j] = make_float4(v[4 * j], v[4 * j + 1], v[4 * j + 2], v[4 * j + 3]);
}

// ---------------------------------------------------------------------------
// Kernel 2: transpose w [KN][KC] -> wT [KC][KN]  (per-q weight row becomes
// lane-coalesced)
// ---------------------------------------------------------------------------
__global__ __launch_bounds__(256) void transpose_w_kernel(
    const float* __restrict__ w, float* __restrict__ wT) {
  const int t = blockIdx.x * 256 + threadIdx.x;
  if (t >= KC * KN) return;
  const int q = t >> 6;      // 0..575
  const int n = t & 63;      // 0..63
  wT[t] = w[(size_t)n * KC + q];
}

// ---------------------------------------------------------------------------
// Kernel 3: main fused gather+GEMM.
// Block = 256 threads = 4 waves. Each wave owns 4 pixels (block owns 16
// consecutive pixels). lane = output channel n. Each lane accumulates
// acc[px][b] for its n across all q.
// Per q: index is wave-uniform per pixel (readlane -> scalar load of the
// 64B xT row = all 16 batches), weight load is lane-coalesced.
// ---------------------------------------------------------------------------
__global__ __launch_bounds__(256) void hashconv_main_kernel(
    const int* __restrict__ ht, const float* __restrict__ xT,
    const float* __restrict__ wT, float* __restrict__ out) {
  const int tid  = threadIdx.x;
  const int lane = tid & 63;   // = n (output channel)
  const int wv   = tid >> 6;   // wave in block, 0..3
  const int pblk = blockIdx.x * 16;       // block's first pixel
  const int p0   = pblk + wv * 4;         // wave's first pixel

  float acc[4][NB];
#pragma unroll
  for (int px = 0; px < 4; ++px)
#pragma unroll
    for (int b = 0; b < NB; ++b) acc[px][b] = 0.f;

  for (int qc = 0; qc < KC / 64; ++qc) {  // 9 chunks of 64 q's
    // coalesced preload of 64 indices per pixel into lanes
    int idxreg[4];
#pragma unroll
    for (int px = 0; px < 4; ++px)
      idxreg[px] = ht[(size_t)(p0 + px) * KC + qc * 64 + lane];

#pragma unroll 8
    for (int qq = 0; qq < 64; ++qq) {
      const float wval = wT[(size_t)(qc * 64 + qq) * 64 + lane];  // coalesced
#pragma unroll
      for (int px = 0; px < 4; ++px) {
        const int idx = __builtin_amdgcn_readlane(idxreg[px], qq);  // uniform
        const float* xrow = xT + (size_t)idx * NB;  // 64B row, all batches
#pragma unroll
        for (int b = 0; b < NB; ++b)
          acc[px][b] = fmaf(wval, xrow[b], acc[px][b]);
      }
    }
  }

  // ---- store: LDS transpose so global writes are full 64B lines ----
  // out[(b*64+n)*NHW + p], p = pblk + 0..15. Process 4 b's per pass.
  __shared__ float lds[4][16][65];  // [b_sub][px_in_block][n] (+1 pad)
#pragma unroll 1
  for (int bc = 0; bc < 4; ++bc) {
    __syncthreads();
#pragma unroll
    for (int j = 0; j < 4; ++j)
#pragma unroll
      for (int px = 0; px < 4; ++px)
        lds[j][wv * 4 + px][lane] = acc[px][bc * 4 + j];
    __syncthreads();
    const int j = wv;        // 0..3
    const int n = lane;
    const int b = bc * 4 + j;
    float v[16];
#pragma unroll
    for (int px = 0; px < 16; ++px) v[px] = lds[j][px][n];
    float4* dst = (float4*)(out + ((size_t)(b * 64 + n)) * NHW + pblk);
    dst[0] = make_float4(v[0], v[1], v[2], v[3]);
    dst[1] = make_float4(v[4], v[5], v[6], v[7]);
    dst[2] = make_float4(v[8], v[9], v[10], v[11]);
    dst[3] = make_float4(v[12], v[13], v[14], v[15]);
  }
}

// ---------------------------------------------------------------------------
// Fallback (only if workspace is too small): direct gather, slow but correct.
// wave = (b, p); lane = n.
// ---------------------------------------------------------------------------
__global__ __launch_bounds__(256) void hashconv_naive_kernel(
    const int* __restrict__ ht, const float* __restrict__ x,
    const float* __restrict__ w, float* __restrict__ out) {
  const int wave = (blockIdx.x * 256 + threadIdx.x) >> 6;
  const int lane = threadIdx.x & 63;
  const int b = wave >> 14;       // wave = b*NHW + p
  const int p = wave & (NHW - 1);
  float acc = 0.f;
  for (int q = 0; q < KC; ++q) {
    const int idx = __builtin_amdgcn_readlane(
        ht[(size_t)p * KC + q], 0);  // same for all lanes anyway
    const float xv = x[(size_t)b * CHW + idx];
    acc = fmaf(w[(size_t)lane * KC + q], xv, acc);
  }
  out[((size_t)(b * 64 + lane)) * NHW + p] = acc;
}

extern "C" void kernel_launch(void* const* d_in, const int* in_sizes, int n_in,
                              void* d_out, int out_size, void* d_ws, size_t ws_size,
                              hipStream_t stream) {
  const float* x  = (const float*)d_in[0];
  const int*   ht = (const int*)d_in[1];
  const float* w  = (const float*)d_in[2];
  float* out = (float*)d_out;

  const size_t need = (size_t)CHW * NB * sizeof(float) + (size_t)KC * KN * sizeof(float);
  if (ws_size >= need) {
    float* xT = (float*)d_ws;
    float* wT = xT + (size_t)CHW * NB;
    transpose_x_kernel<<<CHW / 256, 256, 0, stream>>>(x, xT);
    transpose_w_kernel<<<(KC * KN + 255) / 256, 256, 0, stream>>>(w, wT);
    hashconv_main_kernel<<<NHW / 16, 256, 0, stream>>>(ht, xT, wT, out);
  } else {
    hashconv_naive_kernel<<<(NB * NHW * 64) / 256, 256, 0, stream>>>(ht, x, w, out);
  }
}

// Round 2
// 210.586 us; speedup vs baseline: 2.4079x; 2.4079x over previous
//
#include <hip/hip_runtime.h>
#include <hip/hip_bf16.h>

#define NB   16          // batch
#define NC   64          // channels
#define NHW  16384       // H*W
#define CHW  1048576     // C*H*W
#define KC   576         // K*C (GEMM K)
#define KN   64          // output channels

typedef __attribute__((ext_vector_type(8))) short bf16x8;
typedef __attribute__((ext_vector_type(4))) float f32x4;

static __device__ __forceinline__ unsigned short f32_to_bf16(float f) {
  unsigned int u = __float_as_uint(f);
  unsigned int r = (u + 0x7FFFu + ((u >> 16) & 1u)) >> 16;  // RNE
  return (unsigned short)r;
}

// ---------------------------------------------------------------------------
// Kernel 1: x [B][CHW] fp32 -> xT [CHW][16] bf16 (32B per row = all batches)
// ---------------------------------------------------------------------------
__global__ __launch_bounds__(256) void transpose_x_bf16(
    const float* __restrict__ x, unsigned short* __restrict__ xT) {
  const int i = blockIdx.x * 256 + threadIdx.x;  // CHW index
  unsigned short u[16];
#pragma unroll
  for (int b = 0; b < NB; ++b) u[b] = f32_to_bf16(x[(size_t)b * CHW + i]);
  int4* dst = (int4*)(xT + (size_t)i * NB);
  dst[0] = ((int4*)u)[0];
  dst[1] = ((int4*)u)[1];
}

// ---------------------------------------------------------------------------
// Kernel 2: pack w [KN][KC] fp32 into MFMA A-fragment order, bf16:
// wP[((ks*4+m)*64 + lane)*8 + j] = w[m*16 + (lane&15)][ks*32 + (lane>>4)*8 + j]
// ---------------------------------------------------------------------------
__global__ __launch_bounds__(256) void prep_w(
    const float* __restrict__ w, unsigned short* __restrict__ wP) {
  const int t = blockIdx.x * 256 + threadIdx.x;  // 0..36863
  const int j  = t & 7;
  const int l  = (t >> 3) & 63;
  const int m  = (t >> 9) & 3;
  const int ks = t >> 11;                        // 0..17
  const int n  = m * 16 + (l & 15);
  const int k  = ks * 32 + (l >> 4) * 8 + j;
  wP[t] = f32_to_bf16(w[(size_t)n * KC + k]);
}

// ---------------------------------------------------------------------------
// Main: per block = 16 pixels. GEMM: out[64 n][256 cols], col = pp*16 + b.
// 4 waves: wave wv owns pixels pp = 4wv..4wv+3 (cols wv*64..wv*64+63).
// K staged in 9 chunks of 64 into LDS [c][64] bf16, XOR-swizzled.
// ---------------------------------------------------------------------------
__global__ __launch_bounds__(256) void hashconv_mfma(
    const int* __restrict__ ht, const unsigned short* __restrict__ xT,
    const unsigned short* __restrict__ wP, float* __restrict__ out) {
  const int tid  = threadIdx.x;
  const int lane = tid & 63;
  const int wv   = tid >> 6;
  const int hi   = lane >> 4;   // 0..3
  const int b16i = lane & 15;   // b (column within 16-tile) for MFMA phases
  const int p0   = blockIdx.x * 16;

  __shared__ unsigned short Gs[256 * 64];  // 32 KiB, also reused by epilogue

  f32x4 acc[4][4];
#pragma unroll
  for (int m = 0; m < 4; ++m)
#pragma unroll
    for (int px = 0; px < 4; ++px) acc[m][px] = (f32x4){0.f, 0.f, 0.f, 0.f};

  // staging lane roles: 8 lanes per gathered row; each lane loads a dword
  // (2 batches) of the 32B xT row.
  const int rsub = lane >> 3;        // 0..7 : row (q) sub-index
  const int bp   = lane & 7;         // batch-pair id -> c pair
  const int s_rd = (b16i & 7) << 3;  // read-side swizzle for this lane

  for (int kc = 0; kc < 9; ++kc) {
    // coalesced ht preload: idxreg[pxl] holds index for q = lane
    int idxreg[4];
#pragma unroll
    for (int pxl = 0; pxl < 4; ++pxl)
      idxreg[pxl] = ht[(p0 + 4 * wv + pxl) * KC + kc * 64 + lane];

    __syncthreads();  // previous chunk's MFMA reads done

    // ---- stage: gather 16px x 64q rows of xT (32B each) into Gs ----
#pragma unroll
    for (int pxl = 0; pxl < 4; ++pxl) {
      const int c0 = (4 * wv + pxl) * 16 + 2 * bp;  // first c of the pair
      const int s0 = (c0 & 7) << 3;
      const int s1 = ((c0 + 1) & 7) << 3;
      unsigned short* g0 = &Gs[c0 * 64];
      unsigned short* g1 = &Gs[(c0 + 1) * 64];
#pragma unroll
      for (int qb = 0; qb < 8; ++qb) {
        const int q   = qb * 8 + rsub;
        const int idx = __shfl(idxreg[pxl], q);
        const unsigned int v =
            *(const unsigned int*)(xT + (size_t)idx * NB + 2 * bp);
        g0[q ^ s0] = (unsigned short)v;
        g1[q ^ s1] = (unsigned short)(v >> 16);
      }
    }
    __syncthreads();

    // ---- compute: 2 k-steps of 32 ----
#pragma unroll
    for (int ks = 0; ks < 2; ++ks) {
      const int ksg = kc * 2 + ks;
      bf16x8 afr[4], bfr[4];
#pragma unroll
      for (int m = 0; m < 4; ++m)
        afr[m] = *(const bf16x8*)(wP + ((size_t)(ksg * 4 + m) * 64 + lane) * 8);
#pragma unroll
      for (int px = 0; px < 4; ++px) {
        const int c  = wv * 64 + px * 16 + b16i;
        const int kb = ks * 32 + hi * 8;
        bfr[px] = *(const bf16x8*)(&Gs[c * 64 + (kb ^ s_rd)]);
      }
#pragma unroll
      for (int m = 0; m < 4; ++m)
#pragma unroll
        for (int px = 0; px < 4; ++px)
          acc[m][px] = __builtin_amdgcn_mfma_f32_16x16x32_bf16(
              afr[m], bfr[px], acc[m][px], 0, 0, 0);
    }
  }

  // ---- epilogue: LDS transpose -> coalesced 64B stores ----
  // C/D layout: col = lane&15 = b, row(n within m-tile) = hi*4 + j, pp = 4wv+px
  float* Ep = (float*)Gs;  // needs 16*16*20*4 = 20.5 KB < 32 KB
  const int tb = tid >> 4, tn = tid & 15;
#pragma unroll
  for (int m = 0; m < 4; ++m) {
    __syncthreads();
#pragma unroll
    for (int px = 0; px < 4; ++px)
#pragma unroll
      for (int j = 0; j < 4; ++j)
        Ep[(b16i * 16 + hi * 4 + j) * 20 + 4 * wv + px] = acc[m][px][j];
    __syncthreads();
    const float* src = &Ep[(tb * 16 + tn) * 20];
    float4 v0 = *(const float4*)(src + 0);
    float4 v1 = *(const float4*)(src + 4);
    float4 v2 = *(const float4*)(src + 8);
    float4 v3 = *(const float4*)(src + 12);
    float4* dst = (float4*)(out + ((size_t)(tb * 64 + m * 16 + tn)) * NHW + p0);
    dst[0] = v0; dst[1] = v1; dst[2] = v2; dst[3] = v3;
  }
}

// ---------------------------------------------------------------------------
// Fallback (workspace too small): direct gather, slow but correct.
// ---------------------------------------------------------------------------
__global__ __launch_bounds__(256) void hashconv_naive_kernel(
    const int* __restrict__ ht, const float* __restrict__ x,
    const float* __restrict__ w, float* __restrict__ out) {
  const int wave = (blockIdx.x * 256 + threadIdx.x) >> 6;
  const int lane = threadIdx.x & 63;
  const int b = wave >> 14;
  const int p = wave & (NHW - 1);
  float acc = 0.f;
  for (int q = 0; q < KC; ++q) {
    const int idx = __builtin_amdgcn_readlane(ht[(size_t)p * KC + q], 0);
    const float xv = x[(size_t)b * CHW + idx];
    acc = fmaf(w[(size_t)lane * KC + q], xv, acc);
  }
  out[((size_t)(b * 64 + lane)) * NHW + p] = acc;
}

extern "C" void kernel_launch(void* const* d_in, const int* in_sizes, int n_in,
                              void* d_out, int out_size, void* d_ws, size_t ws_size,
                              hipStream_t stream) {
  const float* x  = (const float*)d_in[0];
  const int*   ht = (const int*)d_in[1];
  const float* w  = (const float*)d_in[2];
  float* out = (float*)d_out;

  const size_t xT_elems = (size_t)CHW * NB;      // bf16
  const size_t wP_elems = (size_t)18 * 4 * 64 * 8;
  const size_t need = (xT_elems + wP_elems) * sizeof(unsigned short);

  if (ws_size >= need) {
    unsigned short* xT = (unsigned short*)d_ws;
    unsigned short* wP = xT + xT_elems;
    transpose_x_bf16<<<CHW / 256, 256, 0, stream>>>(x, xT);
    prep_w<<<(int)(wP_elems / 256), 256, 0, stream>>>(w, wP);
    hashconv_mfma<<<NHW / 16, 256, 0, stream>>>(ht, xT, wP, out);
  } else {
    hashconv_naive_kernel<<<(NB * NHW * 64) / 256, 256, 0, stream>>>(ht, x, w, out);
  }
}